// Round 1
// baseline (93.380 us; speedup 1.0000x reference)
//
#include <hip/hip_runtime.h>
#include <hip/hip_bf16.h>

// PerPixelConv: out[b,c,h,w] = sum_{dy,dx in 0..2} input_zp[b,c,h+dy-1,w+dx-1] * kernel[b,dy*3+dx,h,w]
// Shapes: input [8,3,720,1280] f32, kernel [8,9,720,1280] f32, out [8,3,720,1280] f32.
// Memory-bound: kernel tensor (265 MB) dominates. Strategy: one thread per
// float4 group of 4 pixels; load 9 kernel float4s once, reuse across 3 channels.

#ifndef PPC_CONSTS
#define PPC_CONSTS
constexpr int PB = 8, PC = 3, PH = 720, PW = 1280;
constexpr int PHW = PH * PW;
constexpr int PWG = PW / 4;              // float4 groups per row
constexpr int PTOTAL = PB * PH * PWG;    // one thread per group
#endif

__global__ __launch_bounds__(256) void PerPixelConv_kernel(
    const float* __restrict__ input,
    const float* __restrict__ kernel,
    float* __restrict__ out)
{
    int idx = blockIdx.x * blockDim.x + threadIdx.x;
    if (idx >= PTOTAL) return;

    int wg = idx % PWG;
    int h  = (idx / PWG) % PH;
    int b  = idx / (PWG * PH);
    int w0 = wg * 4;

    // Load the 9 per-pixel kernel taps for these 4 pixels (float4 each).
    const float* kbase = kernel + (size_t)b * 9 * PHW + (size_t)h * PW + w0;
    float4 kv[9];
    #pragma unroll
    for (int k = 0; k < 9; ++k)
        kv[k] = *reinterpret_cast<const float4*>(kbase + (size_t)k * PHW);

    const float* ibase = input + (size_t)b * PC * PHW;
    float*       obase = out   + (size_t)b * PC * PHW;

    #pragma unroll
    for (int c = 0; c < PC; ++c) {
        float acc0 = 0.f, acc1 = 0.f, acc2 = 0.f, acc3 = 0.f;
        #pragma unroll
        for (int dy = 0; dy < 3; ++dy) {
            int row = h + dy - 1;
            if (row < 0 || row >= PH) continue;   // zero padding (vertical)
            const float* r = ibase + (size_t)c * PHW + (size_t)row * PW + w0;
            // x[i] = input pixel at column w0 + i - 1, i in 0..5
            float4 mid = *reinterpret_cast<const float4*>(r);
            float x0 = (w0 > 0)        ? r[-1] : 0.f;   // zero padding (left)
            float x5 = (w0 + 4 < PW)   ? r[4]  : 0.f;   // zero padding (right)
            float x1 = mid.x, x2 = mid.y, x3 = mid.z, x4 = mid.w;

            float4 k0 = kv[dy * 3 + 0];
            float4 k1 = kv[dy * 3 + 1];
            float4 k2 = kv[dy * 3 + 2];
            // dx = 0: input col = w + dx - 1 -> x[j+0]
            acc0 += x0 * k0.x;  acc1 += x1 * k0.y;  acc2 += x2 * k0.z;  acc3 += x3 * k0.w;
            // dx = 1
            acc0 += x1 * k1.x;  acc1 += x2 * k1.y;  acc2 += x3 * k1.z;  acc3 += x4 * k1.w;
            // dx = 2
            acc0 += x2 * k2.x;  acc1 += x3 * k2.y;  acc2 += x4 * k2.z;  acc3 += x5 * k2.w;
        }
        float4 o;
        o.x = acc0; o.y = acc1; o.z = acc2; o.w = acc3;
        *reinterpret_cast<float4*>(obase + (size_t)c * PHW + (size_t)h * PW + w0) = o;
    }
}

extern "C" void kernel_launch(void* const* d_in, const int* in_sizes, int n_in,
                              void* d_out, int out_size, void* d_ws, size_t ws_size,
                              hipStream_t stream) {
    const float* input  = (const float*)d_in[0];
    const float* kernel = (const float*)d_in[1];
    float* out = (float*)d_out;

    int threads = 256;
    int blocks = (PTOTAL + threads - 1) / threads;
    PerPixelConv_kernel<<<blocks, threads, 0, stream>>>(input, kernel, out);
}

// Round 3
// 83.776 us; speedup vs baseline: 1.1146x; 1.1146x over previous
//
#include <hip/hip_runtime.h>
#include <hip/hip_bf16.h>

// PerPixelConv: out[b,c,h,w] = sum_{dy,dx} input_zp[b,c,h+dy-1,w+dx-1] * kernel[b,dy*3+dx,h,w]
// input [8,3,720,1280] f32, kernel [8,9,720,1280] f32, out [8,3,720,1280] f32.
// Memory-bound. R1/R2: XCD-chunked block swizzle so vertically-adjacent rows land
// on the same XCD's L2 (input halo reuse), + nontemporal on the single-use kernel
// stream and output stream to keep L2 for input. R2: use native ext_vector_type
// for nontemporal builtins (HIP_vector_type is a struct -> builtin rejects it).

#ifndef PPC_CONSTS
#define PPC_CONSTS
constexpr int PB = 8, PC = 3, PH = 720, PW = 1280;
constexpr int PHW = PH * PW;
constexpr int PWG = PW / 4;              // float4 groups per row = 320
constexpr int PTOTAL = PB * PH * PWG;    // 1,843,200 threads
constexpr int PBLK = 256;
constexpr int PNBLK = PTOTAL / PBLK;     // 7200 blocks (exact)
constexpr int PNXCD = 8;
constexpr int PCHUNK = PNBLK / PNXCD;    // 900 (exact: 7200 % 8 == 0 -> bijective)
typedef float f32x4 __attribute__((ext_vector_type(4)));
#endif

__global__ __launch_bounds__(PBLK) void PerPixelConv_kernel(
    const float* __restrict__ input,
    const float* __restrict__ kernel,
    float* __restrict__ out)
{
    // XCD-aware swizzle: physical block p dispatches to XCD p%8 (round-robin).
    // Map so XCD x handles the contiguous logical chunk [x*900, (x+1)*900):
    // consecutive blocks on one XCD are vertically adjacent rows -> L2 halo hits.
    int lb  = (blockIdx.x % PNXCD) * PCHUNK + blockIdx.x / PNXCD;
    int idx = lb * PBLK + threadIdx.x;

    int wg = idx % PWG;
    int h  = (idx / PWG) % PH;
    int b  = idx / (PWG * PH);
    int w0 = wg * 4;

    // 9 per-pixel kernel taps for these 4 pixels (read exactly once -> nontemporal).
    const float* kbase = kernel + (size_t)b * 9 * PHW + (size_t)h * PW + w0;
    f32x4 kv[9];
    #pragma unroll
    for (int k = 0; k < 9; ++k)
        kv[k] = __builtin_nontemporal_load(
                    reinterpret_cast<const f32x4*>(kbase + (size_t)k * PHW));

    const float* ibase = input + (size_t)b * PC * PHW;
    float*       obase = out   + (size_t)b * PC * PHW;

    #pragma unroll
    for (int c = 0; c < PC; ++c) {
        float acc0 = 0.f, acc1 = 0.f, acc2 = 0.f, acc3 = 0.f;
        #pragma unroll
        for (int dy = 0; dy < 3; ++dy) {
            int row = h + dy - 1;
            if (row < 0 || row >= PH) continue;   // zero padding (vertical)
            const float* r = ibase + (size_t)c * PHW + (size_t)row * PW + w0;
            f32x4 mid = *reinterpret_cast<const f32x4*>(r);
            float x0 = (w0 > 0)      ? r[-1] : 0.f;   // zero padding (left)
            float x5 = (w0 + 4 < PW) ? r[4]  : 0.f;   // zero padding (right)
            float x1 = mid.x, x2 = mid.y, x3 = mid.z, x4 = mid.w;

            f32x4 k0 = kv[dy * 3 + 0];
            f32x4 k1 = kv[dy * 3 + 1];
            f32x4 k2 = kv[dy * 3 + 2];
            acc0 += x0 * k0.x;  acc1 += x1 * k0.y;  acc2 += x2 * k0.z;  acc3 += x3 * k0.w;
            acc0 += x1 * k1.x;  acc1 += x2 * k1.y;  acc2 += x3 * k1.z;  acc3 += x4 * k1.w;
            acc0 += x2 * k2.x;  acc1 += x3 * k2.y;  acc2 += x4 * k2.z;  acc3 += x5 * k2.w;
        }
        f32x4 o;
        o.x = acc0; o.y = acc1; o.z = acc2; o.w = acc3;
        __builtin_nontemporal_store(
            o, reinterpret_cast<f32x4*>(obase + (size_t)c * PHW + (size_t)h * PW + w0));
    }
}

extern "C" void kernel_launch(void* const* d_in, const int* in_sizes, int n_in,
                              void* d_out, int out_size, void* d_ws, size_t ws_size,
                              hipStream_t stream) {
    const float* input  = (const float*)d_in[0];
    const float* kernel = (const float*)d_in[1];
    float* out = (float*)d_out;

    PerPixelConv_kernel<<<PNBLK, PBLK, 0, stream>>>(input, kernel, out);
}